// Round 18
// baseline (335.952 us; speedup 1.0000x reference)
//
#include <hip/hip_runtime.h>
#include <math.h>

#define NROWS 64
#define DCOLS 512
#define HCOL  256
#define BDIM  512
#define NWV   8     // waves per block
#define RPW   8     // rows per wave
#define BPB   8     // batches per block: grid = 4096/8 = 512 = 2 blocks/CU

typedef float f32x4 __attribute__((ext_vector_type(4)));

__device__ __forceinline__ void wave_reduce_sum2(float& a, float& b) {
#pragma unroll
    for (int off = 32; off > 0; off >>= 1) {
        a += __shfl_xor(a, off, 64);
        b += __shfl_xor(b, off, 64);
    }
}
__device__ __forceinline__ float wave_reduce_sum(float v) {
#pragma unroll
    for (int off = 32; off > 0; off >>= 1)
        v += __shfl_xor(v, off, 64);
    return v;
}

__device__ __forceinline__ float hsum8(f32x4 a, f32x4 b) {
    return ((a.x + a.y) + (a.z + a.w)) + ((b.x + b.y) + (b.z + b.w));
}
__device__ __forceinline__ float hsumsq8(f32x4 a, f32x4 b) {
    return (a.x*a.x + a.y*a.y + a.z*a.z + a.w*a.w)
         + (b.x*b.x + b.y*b.y + b.z*b.z + b.w*b.w);
}

// tanh(x) = 1 - 2/(exp(2x)+1); correct both signs, saturates at +/-1.
__device__ __forceinline__ float fast_tanh(float x) {
    float e = __expf(2.0f * x);
    return 1.0f - 2.0f / (e + 1.0f);
}

// LDS-ordering barrier: does NOT drain vmcnt.
__device__ __forceinline__ void lds_barrier() {
    asm volatile("s_waitcnt lgkmcnt(0)" ::: "memory");
    __builtin_amdgcn_s_barrier();
}

// async global->LDS: 16B/lane, LDS dest = uniform base + lane*16.
__device__ __forceinline__ void glds16(const float* g, float* l) {
    __builtin_amdgcn_global_load_lds(
        (const __attribute__((address_space(1))) void*)g,
        (__attribute__((address_space(3)))       void*)l,
        16, 0, 0);
}

__global__ __launch_bounds__(BDIM, 4) void fused_ln_attn_kernel(
    const float* __restrict__ emb,
    const float* __restrict__ gamma,
    const float* __restrict__ beta,
    const float* __restrict__ Wv,
    const float* __restrict__ bv,
    float* __restrict__ out,
    int B)
{
    // ~74.1 KiB -> 2 blocks/CU (R10-verified occupancy governor).
    __shared__ __align__(16) float s_buf[NROWS * HCOL];  // x1 staged -> e1 in place
    __shared__ __align__(16) float s_q[2][DCOLS];        // q, double-buffered by t&1
    __shared__ __align__(16) float s_g[DCOLS];
    __shared__ __align__(16) float s_b[DCOLS];
    __shared__ __align__(16) float s_w[DCOLS];
    __shared__ float s_den[2][NWV];

    const int tid  = threadIdx.x;
    const int wave = tid >> 6;
    const int lane = tid & 63;
    const int c0   = lane << 2;
    const int c1   = HCOL + c0;
    const int r0   = wave * RPW;

    s_g[tid] = gamma[tid];
    s_b[tid] = beta[tid];
    s_w[tid] = Wv[tid];
    const float bias = bv[0];

    const int bstart = blockIdx.x * BPB;

    // ---- prologue: stage x1(0) (skip row 0), prefetch cx0(0),
    //      wave 0 computes q(0) into s_q[0] ----
    f32x4 cx0[RPW];
    {
        const float* eb = emb + (size_t)bstart * (NROWS * DCOLS);
#pragma unroll
        for (int i = 0; i < RPW; ++i) {
            const int r = r0 + i;
            if (r != 0) {
                glds16(eb + r * DCOLS + c1, s_buf + r * HCOL);
                cx0[i] = *(const f32x4*)(eb + r * DCOLS + c0);
            }
        }
        if (wave == 0) {
            const f32x4 xa = *(const f32x4*)(eb + c0);
            const f32x4 xb = *(const f32x4*)(eb + c1);
            float s = hsum8(xa, xb), ss = hsumsq8(xa, xb);
            wave_reduce_sum2(s, ss);
            const float mu  = s * (1.0f / (float)DCOLS);
            const float var = ss * (1.0f / (float)DCOLS) - mu * mu;
            const float rs  = rsqrtf(var + 1e-5f);
            *(f32x4*)(&s_q[0][0] + c0) = (xa - mu) * rs * *(const f32x4*)(s_g + c0)
                                         + *(const f32x4*)(s_b + c0);
            *(f32x4*)(&s_q[0][0] + c1) = (xb - mu) * rs * *(const f32x4*)(s_g + c1)
                                         + *(const f32x4*)(s_b + c1);
        }
    }
    asm volatile("s_waitcnt vmcnt(0) lgkmcnt(0)" ::: "memory");
    __builtin_amdgcn_s_barrier();   // params + staged x1(0) + q(0) visible

#pragma unroll 1
    for (int t = 0; t < BPB; ++t) {
        const int bb = bstart + t;
        const float* eb = emb + (size_t)bb * (NROWS * DCOLS);
        float*       ob = out + (size_t)bb * (NROWS * DCOLS);

        // Counted per-wave wait: 8 newest VM ops = last iter's c0 stores
        // (stay in flight); older (restage DMAs, c1 stores, cx0, qx) landed.
        asm volatile("s_waitcnt vmcnt(8)" ::: "memory");
        __builtin_amdgcn_sched_barrier(0);

        const f32x4 g0 = *(const f32x4*)(s_g + c0);
        const f32x4 g1 = *(const f32x4*)(s_g + c1);
        const f32x4 b0 = *(const f32x4*)(s_b + c0);
        const f32x4 b1 = *(const f32x4*)(s_b + c1);

        // ---- Pass 1: LN own rows (row 0 skipped: its e IS q, precomputed) ----
        f32x4 e0[RPW];
#pragma unroll
        for (int i = 0; i < RPW; ++i) {
            const int r = r0 + i;
            if (r == 0) continue;   // wave-uniform
            const f32x4 x0 = cx0[i];
            const f32x4 x1 = *(const f32x4*)(s_buf + r * HCOL + c0);

            float s = hsum8(x0, x1), ss = hsumsq8(x0, x1);
            wave_reduce_sum2(s, ss);

            const float mu  = s * (1.0f / (float)DCOLS);
            const float var = ss * (1.0f / (float)DCOLS) - mu * mu;
            const float rs  = rsqrtf(var + 1e-5f);

            e0[i] = (x0 - mu) * rs * g0 + b0;
            const f32x4 t1 = (x1 - mu) * rs * g1 + b1;
            *(f32x4*)(s_buf + r * HCOL + c0) = t1;   // own slot
        }

        // ---- wave 0: issue next batch's row-0 load (covered by pass 2) ----
        f32x4 qxa, qxb;
        if (wave == 0 && t + 1 < BPB) {
            const float* nb = eb + NROWS * DCOLS;
            qxa = *(const f32x4*)(nb + c0);
            qxb = *(const f32x4*)(nb + c1);
        }

        // ---- prefetch next batch's cx0 (newest loads before pass 2) ----
        if (t + 1 < BPB) {
            const float* nb = eb + NROWS * DCOLS;
#pragma unroll
            for (int i = 0; i < RPW; ++i) {
                const int r = r0 + i;
                if (r != 0) cx0[i] = *(const f32x4*)(nb + r * DCOLS + c0);
            }
        }
        __builtin_amdgcn_sched_barrier(0);

        // q from LDS (published at t-1's barrier / prologue)
        const f32x4 q0 = *(const f32x4*)(&s_q[t & 1][0] + c0);
        const f32x4 q1 = *(const f32x4*)(&s_q[t & 1][0] + c1);
        const f32x4 w0 = *(const f32x4*)(s_w + c0);
        const f32x4 w1 = *(const f32x4*)(s_w + c1);

        // ---- Pass 2: scores + per-wave softmax partials (max-free) ----
        float ex[RPW];
        float denw = 0.0f;
#pragma unroll
        for (int i = 0; i < RPW; ++i) {
            const int r = r0 + i;
            if (r == 0) { ex[i] = 0.0f; continue; }   // wave-uniform
            const f32x4 t1 = *(const f32x4*)(s_buf + r * HCOL + c0);
            float p;
            p  = fast_tanh(q0.x * e0[i].x) * w0.x;
            p += fast_tanh(q0.y * e0[i].y) * w0.y;
            p += fast_tanh(q0.z * e0[i].z) * w0.z;
            p += fast_tanh(q0.w * e0[i].w) * w0.w;
            p += fast_tanh(q1.x * t1.x) * w1.x;
            p += fast_tanh(q1.y * t1.y) * w1.y;
            p += fast_tanh(q1.z * t1.z) * w1.z;
            p += fast_tanh(q1.w * t1.w) * w1.w;
            const float tot = wave_reduce_sum(p) + bias;
            ex[i] = __expf(tot);
            denw += ex[i];
        }
        if (lane == 0) s_den[t & 1][wave] = denw;

        // ---- wave 0: compute q(t+1), publish under the SAME barrier ----
        if (wave == 0 && t + 1 < BPB) {
            float s = hsum8(qxa, qxb), ss = hsumsq8(qxa, qxb);
            wave_reduce_sum2(s, ss);
            const float mu  = s * (1.0f / (float)DCOLS);
            const float var = ss * (1.0f / (float)DCOLS) - mu * mu;
            const float rs  = rsqrtf(var + 1e-5f);
            *(f32x4*)(&s_q[(t + 1) & 1][0] + c0) = (qxa - mu) * rs * g0 + b0;
            *(f32x4*)(&s_q[(t + 1) & 1][0] + c1) = (qxb - mu) * rs * g1 + b1;
        }

        lds_barrier();   // the ONLY block-wide sync: den + q(t+1) visible

        float den = 0.0f;
#pragma unroll
        for (int w = 0; w < NWV; ++w) den += s_den[t & 1][w];
        const float inv = 1.0f / den;

        // ---- Pass 3a: c1-half (row 0 from s_q, a=1) ----
#pragma unroll
        for (int i = 0; i < RPW; ++i) {
            const int r = r0 + i;
            const float a  = (r == 0) ? 1.0f : ex[i] * inv;
            const f32x4 t1 = (r == 0) ? *(const f32x4*)(&s_q[t & 1][0] + c1)
                                      : *(const f32x4*)(s_buf + r * HCOL + c0);
            __builtin_nontemporal_store(t1 * a, (f32x4*)(ob + r * DCOLS + c1));
        }
        asm volatile("s_waitcnt lgkmcnt(0)" ::: "memory");   // slot reads done
        __builtin_amdgcn_sched_barrier(0);

        // ---- Pass 3b: restage next batch's x1 (row 0 never staged) ----
        if (t + 1 < BPB) {
            const float* nb = eb + NROWS * DCOLS;
#pragma unroll
            for (int i = 0; i < RPW; ++i) {
                const int r = r0 + i;
                if (r != 0) glds16(nb + r * DCOLS + c1, s_buf + r * HCOL);
            }
        }
        __builtin_amdgcn_sched_barrier(0);

        // ---- Pass 3c: c0-half stores LAST (the 8 newest VM ops) ----
#pragma unroll
        for (int i = 0; i < RPW; ++i) {
            const int r = r0 + i;
            const float a  = (r == 0) ? 1.0f : ex[i] * inv;
            const f32x4 v0 = (r == 0) ? *(const f32x4*)(&s_q[t & 1][0] + c0)
                                      : e0[i];
            __builtin_nontemporal_store(v0 * a, (f32x4*)(ob + r * DCOLS + c0));
        }
    }
}

extern "C" void kernel_launch(void* const* d_in, const int* in_sizes, int n_in,
                              void* d_out, int out_size, void* d_ws, size_t ws_size,
                              hipStream_t stream) {
    const float* emb   = (const float*)d_in[0];
    const float* gamma = (const float*)d_in[1];
    const float* beta  = (const float*)d_in[2];
    const float* Wv    = (const float*)d_in[3];
    const float* bv    = (const float*)d_in[4];
    float* out = (float*)d_out;

    const int B = in_sizes[0] / (NROWS * DCOLS);
    const int grid = (B + BPB - 1) / BPB;
    fused_ln_attn_kernel<<<grid, BDIM, 0, stream>>>(emb, gamma, beta, Wv, bv, out, B);
}

// Round 19
// 284.359 us; speedup vs baseline: 1.1814x; 1.1814x over previous
//
#include <hip/hip_runtime.h>
#include <math.h>

#define NROWS 64
#define DCOLS 512
#define HCOL  256
#define BDIM  512
#define NWV   8     // waves per block
#define RPW   8     // rows per wave
#define BPB   8     // batches per block: grid = 4096/8 = 512 = 2 blocks/CU

typedef float f32x4 __attribute__((ext_vector_type(4)));

__device__ __forceinline__ void wave_reduce_sum2(float& a, float& b) {
#pragma unroll
    for (int off = 32; off > 0; off >>= 1) {
        a += __shfl_xor(a, off, 64);
        b += __shfl_xor(b, off, 64);
    }
}
__device__ __forceinline__ float wave_reduce_sum(float v) {
#pragma unroll
    for (int off = 32; off > 0; off >>= 1)
        v += __shfl_xor(v, off, 64);
    return v;
}

__device__ __forceinline__ float hsum8(f32x4 a, f32x4 b) {
    return ((a.x + a.y) + (a.z + a.w)) + ((b.x + b.y) + (b.z + b.w));
}
__device__ __forceinline__ float hsumsq8(f32x4 a, f32x4 b) {
    return (a.x*a.x + a.y*a.y + a.z*a.z + a.w*a.w)
         + (b.x*b.x + b.y*b.y + b.z*b.z + b.w*b.w);
}

// tanh(x) = 1 - 2/(exp(2x)+1); correct both signs, saturates at +/-1.
__device__ __forceinline__ float fast_tanh(float x) {
    float e = __expf(2.0f * x);
    return 1.0f - 2.0f / (e + 1.0f);
}

// LDS-ordering barrier: does NOT drain vmcnt.
__device__ __forceinline__ void lds_barrier() {
    asm volatile("s_waitcnt lgkmcnt(0)" ::: "memory");
    __builtin_amdgcn_s_barrier();
}

// async global->LDS: 16B/lane, LDS dest = uniform base + lane*16.
__device__ __forceinline__ void glds16(const float* g, float* l) {
    __builtin_amdgcn_global_load_lds(
        (const __attribute__((address_space(1))) void*)g,
        (__attribute__((address_space(3)))       void*)l,
        16, 0, 0);
}

__global__ __launch_bounds__(BDIM, 4) void fused_ln_attn_kernel(
    const float* __restrict__ emb,
    const float* __restrict__ gamma,
    const float* __restrict__ beta,
    const float* __restrict__ Wv,
    const float* __restrict__ bv,
    float* __restrict__ out,
    int B)
{
    // ~75.9 KiB -> 2 blocks/CU (R10-verified occupancy governor).
    __shared__ __align__(16) float s_buf[NROWS * HCOL];  // x1 staged -> e1 in place
    __shared__ __align__(16) float s_qx[2][DCOLS];       // row-0 x, staged 2 ahead
    __shared__ __align__(16) float s_g[DCOLS];
    __shared__ __align__(16) float s_b[DCOLS];
    __shared__ __align__(16) float s_w[DCOLS];
    __shared__ float s_den[2][NWV];

    const int tid  = threadIdx.x;
    const int wave = tid >> 6;
    const int lane = tid & 63;
    const int c0   = lane << 2;
    const int c1   = HCOL + c0;
    const int r0   = wave * RPW;

    s_g[tid] = gamma[tid];
    s_b[tid] = beta[tid];
    s_w[tid] = Wv[tid];
    const float bias = bv[0];

    const int bstart = blockIdx.x * BPB;

    // ---- prologue: stage x1(0) rows>=1, cx0(0); stage row-0 x of batches
    //      0 and 1 into s_qx[0]/s_qx[1] (wave 0, DMA, no reg state) ----
    f32x4 cx0[RPW];
    {
        const float* eb = emb + (size_t)bstart * (NROWS * DCOLS);
#pragma unroll
        for (int i = 0; i < RPW; ++i) {
            const int r = r0 + i;
            if (r != 0) glds16(eb + r * DCOLS + c1, s_buf + r * HCOL);
            cx0[i] = *(const f32x4*)(eb + r * DCOLS + c0);  // uniform count
        }
        if (wave == 0) {
            glds16(eb + c0,         &s_qx[0][0]);
            glds16(eb + HCOL + c0,  &s_qx[0][HCOL]);
            if (BPB > 1) {
                const float* nb = eb + NROWS * DCOLS;
                glds16(nb + c0,        &s_qx[1][0]);
                glds16(nb + HCOL + c0, &s_qx[1][HCOL]);
            }
        }
    }
    asm volatile("s_waitcnt vmcnt(0) lgkmcnt(0)" ::: "memory");
    __builtin_amdgcn_s_barrier();   // params + x1(0) + qx(0) + qx(1) visible

#pragma unroll 1
    for (int t = 0; t < BPB; ++t) {
        const int bb = bstart + t;
        const float* eb = emb + (size_t)bb * (NROWS * DCOLS);
        float*       ob = out + (size_t)bb * (NROWS * DCOLS);

        // Counted per-wave wait: 8 newest VM ops = last iter's c0 stores
        // (stay in flight); older (restage+qx DMAs, c1 stores, cx0) landed.
        asm volatile("s_waitcnt vmcnt(8)" ::: "memory");
        __builtin_amdgcn_sched_barrier(0);

        const f32x4 g0 = *(const f32x4*)(s_g + c0);
        const f32x4 g1 = *(const f32x4*)(s_g + c1);
        const f32x4 b0 = *(const f32x4*)(s_b + c0);
        const f32x4 b1 = *(const f32x4*)(s_b + c1);

        // ---- Pass 1: LN own rows (row 0 skipped: handled via q) ----
        f32x4 e0[RPW];
#pragma unroll
        for (int i = 0; i < RPW; ++i) {
            const int r = r0 + i;
            if (r == 0) continue;   // wave-uniform (wave 0, i=0 only)
            const f32x4 x0 = cx0[i];
            const f32x4 x1 = *(const f32x4*)(s_buf + r * HCOL + c0);

            float s = hsum8(x0, x1), ss = hsumsq8(x0, x1);
            wave_reduce_sum2(s, ss);

            const float mu  = s * (1.0f / (float)DCOLS);
            const float var = ss * (1.0f / (float)DCOLS) - mu * mu;
            const float rs  = rsqrtf(var + 1e-5f);

            e0[i] = (x0 - mu) * rs * g0 + b0;
            const f32x4 t1 = (x1 - mu) * rs * g1 + b1;
            *(f32x4*)(s_buf + r * HCOL + c0) = t1;   // own slot
        }

        // ---- prefetch next batch's cx0 (newest loads before pass 2) ----
        if (t + 1 < BPB) {
            const float* nb = eb + NROWS * DCOLS;
#pragma unroll
            for (int i = 0; i < RPW; ++i)
                cx0[i] = *(const f32x4*)(nb + (r0 + i) * DCOLS + c0);
        }
        __builtin_amdgcn_sched_barrier(0);

        // ---- q: EVERY wave computes it redundantly from s_qx (LDS-hot,
        //      identical inputs + op order -> identical results; visibility
        //      guaranteed by prologue / (t-1) den barrier + wave-0 vmcnt) ----
        f32x4 q0, q1;
        {
            const f32x4 xa = *(const f32x4*)(&s_qx[t & 1][0] + c0);
            const f32x4 xb = *(const f32x4*)(&s_qx[t & 1][HCOL] + c0);
            float s = hsum8(xa, xb), ss = hsumsq8(xa, xb);
            wave_reduce_sum2(s, ss);
            const float mu  = s * (1.0f / (float)DCOLS);
            const float var = ss * (1.0f / (float)DCOLS) - mu * mu;
            const float rs  = rsqrtf(var + 1e-5f);
            q0 = (xa - mu) * rs * g0 + b0;
            q1 = (xb - mu) * rs * g1 + b1;
        }

        const f32x4 w0 = *(const f32x4*)(s_w + c0);
        const f32x4 w1 = *(const f32x4*)(s_w + c1);

        // ---- Pass 2: scores + per-wave softmax partials (max-free) ----
        float ex[RPW];
        float denw = 0.0f;
#pragma unroll
        for (int i = 0; i < RPW; ++i) {
            const int r = r0 + i;
            if (r == 0) { ex[i] = 0.0f; continue; }
            const f32x4 t1 = *(const f32x4*)(s_buf + r * HCOL + c0);
            float p;
            p  = fast_tanh(q0.x * e0[i].x) * w0.x;
            p += fast_tanh(q0.y * e0[i].y) * w0.y;
            p += fast_tanh(q0.z * e0[i].z) * w0.z;
            p += fast_tanh(q0.w * e0[i].w) * w0.w;
            p += fast_tanh(q1.x * t1.x) * w1.x;
            p += fast_tanh(q1.y * t1.y) * w1.y;
            p += fast_tanh(q1.z * t1.z) * w1.z;
            p += fast_tanh(q1.w * t1.w) * w1.w;
            const float tot = wave_reduce_sum(p) + bias;
            ex[i] = __expf(tot);
            denw += ex[i];
        }
        if (lane == 0) s_den[t & 1][wave] = denw;

        lds_barrier();   // the ONLY block-wide sync per iteration

        float den = 0.0f;
#pragma unroll
        for (int w = 0; w < NWV; ++w) den += s_den[t & 1][w];
        const float inv = 1.0f / den;

        // ---- Pass 3a: c1-half (row 0 from q1, a=1) ----
#pragma unroll
        for (int i = 0; i < RPW; ++i) {
            const int r = r0 + i;
            const float a  = (r == 0) ? 1.0f : ex[i] * inv;
            const f32x4 t1 = (r == 0) ? q1
                                      : *(const f32x4*)(s_buf + r * HCOL + c0);
            __builtin_nontemporal_store(t1 * a, (f32x4*)(ob + r * DCOLS + c1));
        }
        asm volatile("s_waitcnt lgkmcnt(0)" ::: "memory");   // slot reads done
        __builtin_amdgcn_sched_barrier(0);

        // ---- Pass 3b: restage next batch's x1 (rows>=1) + qx(t+2) DMA ----
        if (t + 1 < BPB) {
            const float* nb = eb + NROWS * DCOLS;
#pragma unroll
            for (int i = 0; i < RPW; ++i) {
                const int r = r0 + i;
                if (r != 0) glds16(nb + r * DCOLS + c1, s_buf + r * HCOL);
            }
        }
        if (wave == 0 && t + 2 < BPB) {
            const float* nb2 = eb + 2 * NROWS * DCOLS;
            glds16(nb2 + c0,        &s_qx[t & 1][0]);
            glds16(nb2 + HCOL + c0, &s_qx[t & 1][HCOL]);
        }
        __builtin_amdgcn_sched_barrier(0);

        // ---- Pass 3c: c0-half stores LAST (the 8 newest VM ops) ----
#pragma unroll
        for (int i = 0; i < RPW; ++i) {
            const int r = r0 + i;
            const float a  = (r == 0) ? 1.0f : ex[i] * inv;
            const f32x4 v0 = (r == 0) ? q0 : e0[i];
            __builtin_nontemporal_store(v0 * a, (f32x4*)(ob + r * DCOLS + c0));
        }
    }
}

extern "C" void kernel_launch(void* const* d_in, const int* in_sizes, int n_in,
                              void* d_out, int out_size, void* d_ws, size_t ws_size,
                              hipStream_t stream) {
    const float* emb   = (const float*)d_in[0];
    const float* gamma = (const float*)d_in[1];
    const float* beta  = (const float*)d_in[2];
    const float* Wv    = (const float*)d_in[3];
    const float* bv    = (const float*)d_in[4];
    float* out = (float*)d_out;

    const int B = in_sizes[0] / (NROWS * DCOLS);
    const int grid = (B + BPB - 1) / BPB;
    fused_ln_attn_kernel<<<grid, BDIM, 0, stream>>>(emb, gamma, beta, Wv, bv, out, B);
}

// Round 20
// 220.364 us; speedup vs baseline: 1.5245x; 1.2904x over previous
//
#include <hip/hip_runtime.h>
#include <math.h>

#define NROWS 64
#define DCOLS 512
#define HCOL  256
#define BDIM  512
#define NWV   8     // waves per block
#define RPW   8     // rows per wave
#define BPB   4     // batches per block: grid = 4096/4 = 1024 -> 4 block
                    // generations per CU; successive generations start
                    // phase-offset from survivors (convoy decorrelation)

typedef float f32x4 __attribute__((ext_vector_type(4)));

__device__ __forceinline__ void wave_reduce_sum2(float& a, float& b) {
#pragma unroll
    for (int off = 32; off > 0; off >>= 1) {
        a += __shfl_xor(a, off, 64);
        b += __shfl_xor(b, off, 64);
    }
}
__device__ __forceinline__ float wave_reduce_sum(float v) {
#pragma unroll
    for (int off = 32; off > 0; off >>= 1)
        v += __shfl_xor(v, off, 64);
    return v;
}

__device__ __forceinline__ float hsum8(f32x4 a, f32x4 b) {
    return ((a.x + a.y) + (a.z + a.w)) + ((b.x + b.y) + (b.z + b.w));
}
__device__ __forceinline__ float hsumsq8(f32x4 a, f32x4 b) {
    return (a.x*a.x + a.y*a.y + a.z*a.z + a.w*a.w)
         + (b.x*b.x + b.y*b.y + b.z*b.z + b.w*b.w);
}

// tanh(x) = 1 - 2/(exp(2x)+1); correct both signs, saturates at +/-1.
__device__ __forceinline__ float fast_tanh(float x) {
    float e = __expf(2.0f * x);
    return 1.0f - 2.0f / (e + 1.0f);
}

// LDS-ordering barrier: does NOT drain vmcnt.
__device__ __forceinline__ void lds_barrier() {
    asm volatile("s_waitcnt lgkmcnt(0)" ::: "memory");
    __builtin_amdgcn_s_barrier();
}

// async global->LDS: 16B/lane, LDS dest = uniform base + lane*16.
__device__ __forceinline__ void glds16(const float* g, float* l) {
    __builtin_amdgcn_global_load_lds(
        (const __attribute__((address_space(1))) void*)g,
        (__attribute__((address_space(3)))       void*)l,
        16, 0, 0);
}

__global__ __launch_bounds__(BDIM, 4) void fused_ln_attn_kernel(
    const float* __restrict__ emb,
    const float* __restrict__ gamma,
    const float* __restrict__ beta,
    const float* __restrict__ Wv,
    const float* __restrict__ bv,
    float* __restrict__ out,
    int B)
{
    // ~70.3 KiB -> 2 blocks/CU (R10-verified occupancy governor).
    __shared__ __align__(16) float s_buf[NROWS * HCOL];  // x1 staged -> e1 in place
    __shared__ __align__(16) float s_q[DCOLS];
    __shared__ __align__(16) float s_g[DCOLS];
    __shared__ __align__(16) float s_b[DCOLS];
    __shared__ __align__(16) float s_w[DCOLS];
    __shared__ float s_den[2][NWV];

    const int tid  = threadIdx.x;
    const int wave = tid >> 6;
    const int lane = tid & 63;
    const int c0   = lane << 2;
    const int c1   = HCOL + c0;
    const int r0   = wave * RPW;

    s_g[tid] = gamma[tid];
    s_b[tid] = beta[tid];
    s_w[tid] = Wv[tid];
    const float bias = bv[0];

    const int bstart = blockIdx.x * BPB;

    // ---- prologue: stage x1(0) via DMA, prefetch cx0(0) into regs ----
    f32x4 cx0[RPW];
    {
        const float* eb = emb + (size_t)bstart * (NROWS * DCOLS);
#pragma unroll
        for (int i = 0; i < RPW; ++i) {
            const int r = r0 + i;
            glds16(eb + r * DCOLS + c1, s_buf + r * HCOL);
            cx0[i] = *(const f32x4*)(eb + r * DCOLS + c0);
        }
    }
    asm volatile("s_waitcnt vmcnt(0) lgkmcnt(0)" ::: "memory");
    __builtin_amdgcn_s_barrier();   // params + staged x1(0) visible

#pragma unroll 1
    for (int t = 0; t < BPB; ++t) {
        const int bb = bstart + t;
        const float* eb = emb + (size_t)bb * (NROWS * DCOLS);
        float*       ob = out + (size_t)bb * (NROWS * DCOLS);

        // Counted per-wave wait: 8 newest VM ops = last iter's c0 stores
        // (stay in flight); older (restage DMAs, c1 stores, cx0 prefetch)
        // guaranteed landed. t=0: no-op.
        asm volatile("s_waitcnt vmcnt(8)" ::: "memory");
        __builtin_amdgcn_sched_barrier(0);

        // ---- Pass 1: LN; e0 -> regs, e1 overwrites its x1 slot in LDS ----
        f32x4 e0[RPW];
        {
            const f32x4 g0 = *(const f32x4*)(s_g + c0);
            const f32x4 g1 = *(const f32x4*)(s_g + c1);
            const f32x4 b0 = *(const f32x4*)(s_b + c0);
            const f32x4 b1 = *(const f32x4*)(s_b + c1);
#pragma unroll
            for (int i = 0; i < RPW; ++i) {
                const int r = r0 + i;
                const f32x4 x0 = cx0[i];
                const f32x4 x1 = *(const f32x4*)(s_buf + r * HCOL + c0);

                float s = hsum8(x0, x1), ss = hsumsq8(x0, x1);
                wave_reduce_sum2(s, ss);

                const float mu  = s * (1.0f / (float)DCOLS);
                const float var = ss * (1.0f / (float)DCOLS) - mu * mu;
                const float rs  = rsqrtf(var + 1e-5f);

                e0[i] = (x0 - mu) * rs * g0 + b0;
                const f32x4 t1 = (x1 - mu) * rs * g1 + b1;
                *(f32x4*)(s_buf + r * HCOL + c0) = t1;   // own slot, in place

                if (wave == 0 && i == 0) {   // publish q
                    *(f32x4*)(s_q + c0) = e0[0];
                    *(f32x4*)(s_q + c1) = t1;
                }
            }
        }

        // ---- prefetch next batch's cx0 ----
        if (t + 1 < BPB) {
            const float* nb = eb + NROWS * DCOLS;
#pragma unroll
            for (int i = 0; i < RPW; ++i)
                cx0[i] = *(const f32x4*)(nb + (r0 + i) * DCOLS + c0);
        }
        __builtin_amdgcn_sched_barrier(0);

        lds_barrier();   // barrier 1: q + e1 visible

        const f32x4 q0 = *(const f32x4*)(s_q + c0);
        const f32x4 q1 = *(const f32x4*)(s_q + c1);
        const f32x4 w0 = *(const f32x4*)(s_w + c0);
        const f32x4 w1 = *(const f32x4*)(s_w + c1);

        // ---- Pass 2: scores + per-wave softmax partials (max-free:
        //      |score| <= sum|Wv_d| + |bv| ~ 18, f32 exp is safe) ----
        float ex[RPW];
        float denw = 0.0f;
#pragma unroll
        for (int i = 0; i < RPW; ++i) {
            const int r = r0 + i;
            const f32x4 t1 = *(const f32x4*)(s_buf + r * HCOL + c0);
            float p;
            p  = fast_tanh(q0.x * e0[i].x) * w0.x;
            p += fast_tanh(q0.y * e0[i].y) * w0.y;
            p += fast_tanh(q0.z * e0[i].z) * w0.z;
            p += fast_tanh(q0.w * e0[i].w) * w0.w;
            p += fast_tanh(q1.x * t1.x) * w1.x;
            p += fast_tanh(q1.y * t1.y) * w1.y;
            p += fast_tanh(q1.z * t1.z) * w1.z;
            p += fast_tanh(q1.w * t1.w) * w1.w;
            const float tot = wave_reduce_sum(p) + bias;
            const float e   = __expf(tot);
            ex[i] = (r == 0) ? 0.0f : e;
            denw += ex[i];
        }
        if (lane == 0) s_den[t & 1][wave] = denw;

        lds_barrier();   // barrier 2: partial denominators visible

        float den = 0.0f;
#pragma unroll
        for (int w = 0; w < NWV; ++w) den += s_den[t & 1][w];
        const float inv = 1.0f / den;

        // ---- Pass 3a: c1-half -- read slot, scale, store (frees slot).
        //      Row 0 through the uniform path with a=1 (it's q). ----
#pragma unroll
        for (int i = 0; i < RPW; ++i) {
            const int r = r0 + i;
            const float a  = (r == 0) ? 1.0f : ex[i] * inv;
            const f32x4 t1 = *(const f32x4*)(s_buf + r * HCOL + c0);
            __builtin_nontemporal_store(t1 * a, (f32x4*)(ob + r * DCOLS + c1));
        }
        asm volatile("s_waitcnt lgkmcnt(0)" ::: "memory");   // slot reads done
        __builtin_amdgcn_sched_barrier(0);

        // ---- Pass 3b: restage next batch's x1 into the freed slots ----
        if (t + 1 < BPB) {
            const float* nb = eb + NROWS * DCOLS;
#pragma unroll
            for (int i = 0; i < RPW; ++i)
                glds16(nb + (r0 + i) * DCOLS + c1, s_buf + (r0 + i) * HCOL);
        }
        __builtin_amdgcn_sched_barrier(0);

        // ---- Pass 3c: c0-half stores LAST (the 8 newest VM ops) ----
#pragma unroll
        for (int i = 0; i < RPW; ++i) {
            const int r = r0 + i;
            const float a = (r == 0) ? 1.0f : ex[i] * inv;
            __builtin_nontemporal_store(e0[i] * a, (f32x4*)(ob + r * DCOLS + c0));
        }
    }
}

extern "C" void kernel_launch(void* const* d_in, const int* in_sizes, int n_in,
                              void* d_out, int out_size, void* d_ws, size_t ws_size,
                              hipStream_t stream) {
    const float* emb   = (const float*)d_in[0];
    const float* gamma = (const float*)d_in[1];
    const float* beta  = (const float*)d_in[2];
    const float* Wv    = (const float*)d_in[3];
    const float* bv    = (const float*)d_in[4];
    float* out = (float*)d_out;

    const int B = in_sizes[0] / (NROWS * DCOLS);
    const int grid = (B + BPB - 1) / BPB;
    fused_ln_attn_kernel<<<grid, BDIM, 0, stream>>>(emb, gamma, beta, Wv, bv, out, B);
}

// Round 21
// 220.031 us; speedup vs baseline: 1.5268x; 1.0015x over previous
//
#include <hip/hip_runtime.h>
#include <math.h>

#define NROWS 64
#define DCOLS 512
#define HCOL  256
#define BDIM  512
#define NWV   8     // waves per block
#define RPW   8     // rows per wave; one batch per block, grid = 4096

typedef float f32x4 __attribute__((ext_vector_type(4)));
typedef unsigned short u16x4 __attribute__((ext_vector_type(4)));

__device__ __forceinline__ void wave_reduce_sum2(float& a, float& b) {
#pragma unroll
    for (int off = 32; off > 0; off >>= 1) {
        a += __shfl_xor(a, off, 64);
        b += __shfl_xor(b, off, 64);
    }
}
__device__ __forceinline__ float wave_reduce_sum(float v) {
#pragma unroll
    for (int off = 32; off > 0; off >>= 1)
        v += __shfl_xor(v, off, 64);
    return v;
}

__device__ __forceinline__ float hsum8(f32x4 a, f32x4 b) {
    return ((a.x + a.y) + (a.z + a.w)) + ((b.x + b.y) + (b.z + b.w));
}
__device__ __forceinline__ float hsumsq8(f32x4 a, f32x4 b) {
    return (a.x*a.x + a.y*a.y + a.z*a.z + a.w*a.w)
         + (b.x*b.x + b.y*b.y + b.z*b.z + b.w*b.w);
}

// tanh(x) = 1 - 2/(exp(2x)+1); correct both signs, saturates at +/-1.
__device__ __forceinline__ float fast_tanh(float x) {
    float e = __expf(2.0f * x);
    return 1.0f - 2.0f / (e + 1.0f);
}

// bf16 pack/unpack (RNE), header-free
__device__ __forceinline__ unsigned short f2b(float f) {
    union { float f; unsigned int u; } v; v.f = f;
    unsigned int r = (v.u + 0x7FFFu + ((v.u >> 16) & 1u)) >> 16;
    return (unsigned short)r;
}
__device__ __forceinline__ float b2f(unsigned short h) {
    union { unsigned int u; float f; } v; v.u = ((unsigned int)h) << 16;
    return v.f;
}

// LDS-ordering barrier: does NOT drain vmcnt (nt-stores stay in flight).
__device__ __forceinline__ void lds_barrier() {
    asm volatile("s_waitcnt lgkmcnt(0)" ::: "memory");
    __builtin_amdgcn_s_barrier();
}

__global__ __launch_bounds__(BDIM, 4) void fused_ln_attn_kernel(
    const float* __restrict__ emb,
    const float* __restrict__ gamma,
    const float* __restrict__ beta,
    const float* __restrict__ Wv,
    const float* __restrict__ bv,
    float* __restrict__ out)
{
    // ~39.1 KiB -> 4 blocks/CU (VGPR<=64) or 3 (<=85): 24-32 waves/CU of
    // TLP + 3-4 independent barrier domains. bf16 e1 is the LDS enabler
    // (abs err ~0.008 << 0.10 threshold).
    __shared__ unsigned short      s_e1[NROWS * HCOL];  // 32 KiB, bf16 e1
    __shared__ __align__(16) float s_q[DCOLS];          // fp32 q (exact)
    __shared__ __align__(16) float s_g[DCOLS];
    __shared__ __align__(16) float s_b[DCOLS];
    __shared__ unsigned short      s_w[DCOLS];          // bf16 Wv
    __shared__ float s_den[NWV];

    const int tid  = threadIdx.x;
    const int wave = tid >> 6;
    const int lane = tid & 63;
    const int c0   = lane << 2;
    const int c1   = HCOL + c0;
    const int r0   = wave * RPW;

    s_g[tid] = gamma[tid];
    s_b[tid] = beta[tid];
    s_w[tid] = f2b(Wv[tid]);
    const float bias = bv[0];

    const size_t base = (size_t)blockIdx.x * (size_t)(NROWS * DCOLS);
    const float* eb = emb + base;
    float*       ob = out + base;

    lds_barrier();   // params visible

    // ---- Pass 1: LN own rows; e0 -> regs (fp32), e1 -> LDS (bf16) ----
    f32x4 e0[RPW];
    {
        const f32x4 g0 = *(const f32x4*)(s_g + c0);
        const f32x4 g1 = *(const f32x4*)(s_g + c1);
        const f32x4 b0 = *(const f32x4*)(s_b + c0);
        const f32x4 b1 = *(const f32x4*)(s_b + c1);
#pragma unroll
        for (int i = 0; i < RPW; ++i) {
            const int r = r0 + i;
            const f32x4 x0 = *(const f32x4*)(eb + r * DCOLS + c0);
            const f32x4 x1 = *(const f32x4*)(eb + r * DCOLS + c1);

            float s = hsum8(x0, x1), ss = hsumsq8(x0, x1);
            wave_reduce_sum2(s, ss);

            const float mu  = s * (1.0f / (float)DCOLS);
            const float var = ss * (1.0f / (float)DCOLS) - mu * mu;
            const float rs  = rsqrtf(var + 1e-5f);

            e0[i] = (x0 - mu) * rs * g0 + b0;
            const f32x4 t1 = (x1 - mu) * rs * g1 + b1;

            u16x4 p;
            p.x = f2b(t1.x); p.y = f2b(t1.y); p.z = f2b(t1.z); p.w = f2b(t1.w);
            *(u16x4*)(s_e1 + r * HCOL + c0) = p;   // own slot

            if (wave == 0 && i == 0) {
                // query row: publish exact fp32 q + write row 0 now
                *(f32x4*)(s_q + c0) = e0[0];
                *(f32x4*)(s_q + c1) = t1;
                __builtin_nontemporal_store(e0[0], (f32x4*)(ob + c0));
                __builtin_nontemporal_store(t1,    (f32x4*)(ob + c1));
            }
        }
    }

    lds_barrier();   // barrier 1: q + e1 visible

    const f32x4 q0 = *(const f32x4*)(s_q + c0);
    const f32x4 q1 = *(const f32x4*)(s_q + c1);
    f32x4 w0, w1;
    {
        const u16x4 wa = *(const u16x4*)(s_w + c0);
        const u16x4 wb = *(const u16x4*)(s_w + c1);
        w0.x = b2f(wa.x); w0.y = b2f(wa.y); w0.z = b2f(wa.z); w0.w = b2f(wa.w);
        w1.x = b2f(wb.x); w1.y = b2f(wb.y); w1.z = b2f(wb.z); w1.w = b2f(wb.w);
    }

    // ---- Pass 2: scores + per-wave softmax partials (max-free:
    //      |score| <= sum|Wv_d| + |bv| ~ 18, f32 exp is safe) ----
    float ex[RPW];
    float denw = 0.0f;
#pragma unroll
    for (int i = 0; i < RPW; ++i) {
        const int r = r0 + i;
        const u16x4 pe = *(const u16x4*)(s_e1 + r * HCOL + c0);
        f32x4 e1;
        e1.x = b2f(pe.x); e1.y = b2f(pe.y); e1.z = b2f(pe.z); e1.w = b2f(pe.w);
        float p;
        p  = fast_tanh(q0.x * e0[i].x) * w0.x;
        p += fast_tanh(q0.y * e0[i].y) * w0.y;
        p += fast_tanh(q0.z * e0[i].z) * w0.z;
        p += fast_tanh(q0.w * e0[i].w) * w0.w;
        p += fast_tanh(q1.x * e1.x) * w1.x;
        p += fast_tanh(q1.y * e1.y) * w1.y;
        p += fast_tanh(q1.z * e1.z) * w1.z;
        p += fast_tanh(q1.w * e1.w) * w1.w;
        const float tot = wave_reduce_sum(p) + bias;
        const float e   = __expf(tot);
        ex[i] = (r == 0) ? 0.0f : e;
        denw += ex[i];
    }
    if (lane == 0) s_den[wave] = denw;

    lds_barrier();   // barrier 2: partial denominators visible

    float den = 0.0f;
#pragma unroll
    for (int w = 0; w < NWV; ++w) den += s_den[w];
    const float inv = 1.0f / den;

    // ---- Pass 3: scale + store (row 0 already written in pass 1) ----
#pragma unroll
    for (int i = 0; i < RPW; ++i) {
        const int r = r0 + i;
        if (r == 0) continue;   // wave-uniform
        const float a = ex[i] * inv;
        const u16x4 pe = *(const u16x4*)(s_e1 + r * HCOL + c0);
        f32x4 e1;
        e1.x = b2f(pe.x); e1.y = b2f(pe.y); e1.z = b2f(pe.z); e1.w = b2f(pe.w);
        __builtin_nontemporal_store(e0[i] * a, (f32x4*)(ob + r * DCOLS + c0));
        __builtin_nontemporal_store(e1 * a,    (f32x4*)(ob + r * DCOLS + c1));
    }
}

extern "C" void kernel_launch(void* const* d_in, const int* in_sizes, int n_in,
                              void* d_out, int out_size, void* d_ws, size_t ws_size,
                              hipStream_t stream) {
    const float* emb   = (const float*)d_in[0];
    const float* gamma = (const float*)d_in[1];
    const float* beta  = (const float*)d_in[2];
    const float* Wv    = (const float*)d_in[3];
    const float* bv    = (const float*)d_in[4];
    float* out = (float*)d_out;

    const int B = in_sizes[0] / (NROWS * DCOLS);
    fused_ln_attn_kernel<<<B, BDIM, 0, stream>>>(emb, gamma, beta, Wv, bv, out);
}